// Round 1
// baseline (107.018 us; speedup 1.0000x reference)
//
#include <hip/hip_runtime.h>
#include <math.h>

#define NO_CH   144      // 4*16 + 80
#define NC      80
#define REGMAX  16
#define A_TOT   8400     // 80*80 + 40*40 + 20*20
#define HW0     6400
#define HW1     1600
#define HW2     400

__device__ __forceinline__ float sigmoidf(float x) {
    return 1.0f / (1.0f + __expf(-x));
}

// ---------------------------------------------------------------------------
// Boxes: one thread per (batch, anchor). DFL softmax over 4 groups of 16
// channels, then (anchor +/- dist) * stride. Reads coalesced across lanes
// (consecutive anchors are contiguous in memory for each channel).
// Level boundaries (6400, 8000) are multiples of 64 -> wave-uniform branch.
// ---------------------------------------------------------------------------
__global__ __launch_bounds__(256) void boxes_kernel(
    const float* __restrict__ f0, const float* __restrict__ f1,
    const float* __restrict__ f2, float* __restrict__ out_boxes)
{
    const int a = blockIdx.x * 256 + threadIdx.x;
    const int b = blockIdx.y;
    if (a >= A_TOT) return;

    const float* src;
    int hw;
    float ax, ay, st;
    if (a < HW0) {
        src = f0 + (size_t)b * NO_CH * HW0 + a;
        hw = HW0; ax = (float)(a % 80) + 0.5f; ay = (float)(a / 80) + 0.5f; st = 8.0f;
    } else if (a < HW0 + HW1) {
        const int l = a - HW0;
        src = f1 + (size_t)b * NO_CH * HW1 + l;
        hw = HW1; ax = (float)(l % 40) + 0.5f; ay = (float)(l / 40) + 0.5f; st = 16.0f;
    } else {
        const int l = a - (HW0 + HW1);
        src = f2 + (size_t)b * NO_CH * HW2 + l;
        hw = HW2; ax = (float)(l % 20) + 0.5f; ay = (float)(l / 20) + 0.5f; st = 32.0f;
    }

    float dist[4];
    #pragma unroll
    for (int g = 0; g < 4; ++g) {
        float v[REGMAX];
        float m = -1e30f;
        #pragma unroll
        for (int r = 0; r < REGMAX; ++r) {
            v[r] = src[(size_t)(g * REGMAX + r) * hw];
            m = fmaxf(m, v[r]);
        }
        float se = 0.0f, sw = 0.0f;
        #pragma unroll
        for (int r = 0; r < REGMAX; ++r) {
            const float e = __expf(v[r] - m);
            se += e;
            sw += e * (float)r;
        }
        dist[g] = sw / se;
    }

    float4 box;
    box.x = (ax - dist[0]) * st;
    box.y = (ay - dist[1]) * st;
    box.z = (ax + dist[2]) * st;
    box.w = (ay + dist[3]) * st;
    reinterpret_cast<float4*>(out_boxes)[(size_t)b * A_TOT + a] = box;
}

// ---------------------------------------------------------------------------
// Scores: sigmoid + transpose (b,80,8400) -> (b,8400,80).
// Per block: 64 anchors x 80 channels for one batch. float4 coalesced loads
// along the anchor axis -> LDS tile (pad 65: bank stride 1, conflict-free)
// -> flat contiguous coalesced stores (64*80 floats are contiguous in the
// anchor-major output).
// ---------------------------------------------------------------------------
__global__ __launch_bounds__(256) void scores_kernel(
    const float* __restrict__ f0, const float* __restrict__ f1,
    const float* __restrict__ f2, float* __restrict__ out_scores)
{
    __shared__ float tile[NC][65];   // 80 x 65 floats = 20.8 KB

    const int b  = blockIdx.y;
    const int a0 = blockIdx.x * 64;

    const float* src;   // points at channel 64 (first score channel) of level
    int hw, local;
    if (a0 < HW0) {
        src = f0 + ((size_t)b * NO_CH + 4 * REGMAX) * HW0; hw = HW0; local = a0;
    } else if (a0 < HW0 + HW1) {
        src = f1 + ((size_t)b * NO_CH + 4 * REGMAX) * HW1; hw = HW1; local = a0 - HW0;
    } else {
        src = f2 + ((size_t)b * NO_CH + 4 * REGMAX) * HW2; hw = HW2; local = a0 - (HW0 + HW1);
    }

    const int tid    = threadIdx.x;
    const int nvalid = min(64, A_TOT - a0);

    if (nvalid == 64) {
        // vectorized path: 16 float4 per row, 16 rows per pass, 5 passes
        const int quad = tid & 15;     // which float4 within the 64-anchor row
        const int r0   = tid >> 4;     // 0..15
        #pragma unroll
        for (int i = 0; i < 5; ++i) {
            const int r = r0 + 16 * i;
            const float4 v = *reinterpret_cast<const float4*>(
                src + (size_t)r * hw + local + quad * 4);
            tile[r][quad * 4 + 0] = sigmoidf(v.x);
            tile[r][quad * 4 + 1] = sigmoidf(v.y);
            tile[r][quad * 4 + 2] = sigmoidf(v.z);
            tile[r][quad * 4 + 3] = sigmoidf(v.w);
        }
    } else {
        // tail tile (last 16 anchors): scalar masked path
        const int col = tid & 63;
        const int r0  = tid >> 6;      // 0..3
        if (col < nvalid) {
            #pragma unroll
            for (int i = 0; i < 20; ++i) {
                const int r = r0 + 4 * i;
                const float x = src[(size_t)r * hw + local + col];
                tile[r][col] = sigmoidf(x);
            }
        }
    }
    __syncthreads();

    // contiguous coalesced store: j = local_anchor*80 + channel
    float* dst = out_scores + ((size_t)b * A_TOT + a0) * NC;
    const int total = nvalid * NC;
    for (int j = tid; j < total; j += 256) {
        const int la = j / NC;          // magic-mul, cheap
        const int c  = j - la * NC;
        dst[j] = tile[c][la];           // bank stride 65%32==1 -> conflict-free
    }
}

extern "C" void kernel_launch(void* const* d_in, const int* in_sizes, int n_in,
                              void* d_out, int out_size, void* d_ws, size_t ws_size,
                              hipStream_t stream) {
    const float* f0 = (const float*)d_in[0];
    const float* f1 = (const float*)d_in[1];
    const float* f2 = (const float*)d_in[2];

    const int b = in_sizes[0] / (NO_CH * HW0);   // 64

    float* out_boxes  = (float*)d_out;
    float* out_scores = out_boxes + (size_t)b * A_TOT * 4;

    dim3 gb((A_TOT + 255) / 256, b);
    boxes_kernel<<<gb, dim3(256), 0, stream>>>(f0, f1, f2, out_boxes);

    dim3 gs((A_TOT + 63) / 64, b);
    scores_kernel<<<gs, dim3(256), 0, stream>>>(f0, f1, f2, out_scores);
}